// Round 11
// baseline (99.105 us; speedup 1.0000x reference)
//
#include <hip/hip_runtime.h>
#include <hip/hip_bf16.h>
#include <stdint.h>

#define U_ROWS 4096
#define P_DIM  1024
#define TM     256     // A rows per block
#define TN     128     // B rows (C cols) per block
#define BK     64      // i8 k-bytes per window (2 k-steps of K=32)

typedef int i32x4  __attribute__((ext_vector_type(4)));
typedef int i32x16 __attribute__((ext_vector_type(16)));

// Row L2-normalize (eps-clamped), quantize q = clamp(round(512*x/||x||)).
// Global layout (r9-proven): within each 64-byte k-window, granule g (16 B)
// stored at slot g ^ ((row>>1)&3) -> GEMM fragment ds_read_b128 covers all
// 32 LDS banks exactly once per 8 consecutive rows (conflict-free).
__global__ __launch_bounds__(256) void norm_i8_kernel(
    const float* __restrict__ in1, const float* __restrict__ in2,
    int8_t* __restrict__ out, float* __restrict__ loss_out) {
    const int w = threadIdx.x >> 6, lane = threadIdx.x & 63;
    const int row = blockIdx.x * 4 + w;
    const float* src = (row < U_ROWS) ? (in1 + (size_t)row * P_DIM)
                                      : (in2 + (size_t)(row - U_ROWS) * P_DIM);
    float4 v[4];
    float ss = 0.0f;
    #pragma unroll
    for (int j = 0; j < 4; ++j) {
        v[j] = ((const float4*)src)[lane * 4 + j];   // lane owns 16 elems
        ss += v[j].x * v[j].x + v[j].y * v[j].y + v[j].z * v[j].z + v[j].w * v[j].w;
    }
    #pragma unroll
    for (int off = 32; off > 0; off >>= 1) ss += __shfl_xor(ss, off, 64);
    const float inv = 512.0f / fmaxf(sqrtf(ss), 1e-8f);

    i32x4 d;
    #pragma unroll
    for (int j = 0; j < 4; ++j) {
        int q0 = max(-127, min(127, (int)rintf(v[j].x * inv)));
        int q1 = max(-127, min(127, (int)rintf(v[j].y * inv)));
        int q2 = max(-127, min(127, (int)rintf(v[j].z * inv)));
        int q3 = max(-127, min(127, (int)rintf(v[j].w * inv)));
        d[j] = (q0 & 255) | ((q1 & 255) << 8) | ((q2 & 255) << 16) | (q3 << 24);
    }
    const int w0   = lane >> 2;                  // 64-B k-window 0..15
    const int g    = lane & 3;                   // granule within window
    const int slot = g ^ ((row >> 1) & 3);       // bank-spread swizzle
    *(i32x4*)(out + (size_t)row * P_DIM + w0 * 64 + slot * 16) = d;
    if (blockIdx.x == 0 && threadIdx.x == 0) *loss_out = 0.0f;
}

// C = N1*N2^T fused with sum((1-c)^2); int8 scaled by 512 -> acc = 2^18*cos
// (exact integer accumulation). Block 256x128, 512 thr / 8 waves (4x2 wave
// grid), wave tile 64x64 via 2x2 v_mfma_i32_32x32x32_i8 per K=32 step,
// 2 steps per BK=64 window. Grid 512 = 2 blocks/CU CO-RESIDENT: r10 showed
// one barrier-locked block serializes LDS-read phase vs MFMA phase; two
// independent blocks per CU desync the phases so both pipes stay fed.
// acc[2][2] = 64 AGPR, VGPR ~70 -> ~124 unified regs -> 2-block residency.
// Single-barrier dbuf K-loop (r8/r9 proven). LDS 48 KB/block.
__global__ __launch_bounds__(512) void cosloss_gemm_i8(
    const int8_t* __restrict__ n1, const int8_t* __restrict__ n2,
    float* __restrict__ loss_out) {
    __shared__ __align__(16) uint8_t As[2][TM * BK];   // 2 x 16 KB
    __shared__ __align__(16) uint8_t Bs[2][TN * BK];   // 2 x 8 KB (=48 KB)
    __shared__ float red[8];

    const int tid  = threadIdx.x;
    const int w    = tid >> 6;        // 0..7
    const int lane = tid & 63;

    // XCD swizzle (perf-only): id%8 -> XCD, 4-wide cb stripe per XCD.
    const int id  = blockIdx.x;         // 0..511
    const int xcd = id & 7;
    const int j   = id >> 3;            // 0..63
    const int cb  = xcd * 4 + (j & 3);  // 0..31
    const int rb  = j >> 2;             // 0..15

    const uint8_t* gA = (const uint8_t*)n1 + (size_t)rb * TM * P_DIM;
    const uint8_t* gB = (const uint8_t*)n2 + (size_t)cb * TN * P_DIM;

    // Staging: chunk = 16 rows x 64 B (1 KB); 24 chunks (16 A + 8 B), 3/wave.
    // Lane reads linearly (swizzle lives in the global layout).
    const int srow = lane >> 2;              // 0..15
    const int scol = (lane & 3) * 16;        // byte col within 64-B window
    const int c0   = w * 3;

    i32x16 acc[2][2];
    #pragma unroll
    for (int mi = 0; mi < 2; ++mi)
        #pragma unroll
        for (int ni = 0; ni < 2; ++ni)
            acc[mi][ni] = (i32x16){0,0,0,0,0,0,0,0,0,0,0,0,0,0,0,0};

    const int wr = (w & 3) * 64;      // wave row origin in 256
    const int wc = (w >> 2) * 64;     // wave col origin in 128
    const int lm = lane & 31;         // row within 32
    const int lh = lane >> 5;         // k-half selector (16 B)

    // kt-invariant LDS fragment byte offsets. Step s wants granule
    // gw = 2s + lh of row m, stored at slot gw ^ ((m>>1)&3).
    int aoff[2][2], boff[2][2];
    #pragma unroll
    for (int i = 0; i < 2; ++i) {
        const int m = wr + i * 32 + lm;
        const int n = wc + i * 32 + lm;
        #pragma unroll
        for (int s = 0; s < 2; ++s) {
            aoff[i][s] = m * BK + (((2 * s + lh) ^ ((m >> 1) & 3)) * 16);
            boff[i][s] = n * BK + (((2 * s + lh) ^ ((n >> 1) & 3)) * 16);
        }
    }

    // Prologue: stage window 0 into buffer 0.
    #pragma unroll
    for (int cc = 0; cc < 3; ++cc) {
        const int c = c0 + cc;
        const uint8_t* gsrc = (c < 16)
            ? gA + (size_t)(c * 16 + srow) * P_DIM + scol
            : gB + (size_t)((c - 16) * 16 + srow) * P_DIM + scol;
        uint8_t* sdst = (c < 16) ? As[0] + c * 1024 : Bs[0] + (c - 16) * 1024;
        __builtin_amdgcn_global_load_lds(
            (const __attribute__((address_space(1))) void*)gsrc,
            (__attribute__((address_space(3))) void*)sdst, 16, 0, 0);
    }

    for (int kt = 0; kt < P_DIM / BK; ++kt) {
        const int cur = kt & 1;
        __syncthreads();   // DMA(kt) drained; buf[cur^1] reads all done

        if (kt + 1 < P_DIM / BK) {
            #pragma unroll
            for (int cc = 0; cc < 3; ++cc) {
                const int c = c0 + cc;
                const uint8_t* gsrc = (c < 16)
                    ? gA + (size_t)(c * 16 + srow) * P_DIM + (kt + 1) * BK + scol
                    : gB + (size_t)((c - 16) * 16 + srow) * P_DIM + (kt + 1) * BK + scol;
                uint8_t* sdst = (c < 16) ? As[cur ^ 1] + c * 1024
                                         : Bs[cur ^ 1] + (c - 16) * 1024;
                __builtin_amdgcn_global_load_lds(
                    (const __attribute__((address_space(1))) void*)gsrc,
                    (__attribute__((address_space(3))) void*)sdst, 16, 0, 0);
            }
        }

        #pragma unroll
        for (int s = 0; s < 2; ++s) {
            i32x4 af[2], bf[2];
            #pragma unroll
            for (int i = 0; i < 2; ++i) {
                af[i] = *(const i32x4*)(As[cur] + aoff[i][s]);
                bf[i] = *(const i32x4*)(Bs[cur] + boff[i][s]);
            }
            #pragma unroll
            for (int mi = 0; mi < 2; ++mi)
                #pragma unroll
                for (int ni = 0; ni < 2; ++ni)
                    acc[mi][ni] = __builtin_amdgcn_mfma_i32_32x32x32_i8(
                        af[mi], bf[ni], acc[mi][ni], 0, 0, 0);
        }
    }

    // Epilogue: acc = 2^18 * cos -> sum (1 - acc*2^-18)^2. Layout-agnostic
    // (full-tile sum; every C element appears exactly once).
    float local = 0.0f;
    #pragma unroll
    for (int mi = 0; mi < 2; ++mi)
        #pragma unroll
        for (int ni = 0; ni < 2; ++ni)
            #pragma unroll
            for (int r = 0; r < 16; ++r) {
                const float dd = 1.0f - (float)acc[mi][ni][r] * (1.0f / 262144.0f);
                local += dd * dd;
            }
    #pragma unroll
    for (int off = 32; off > 0; off >>= 1) local += __shfl_down(local, off, 64);
    if (lane == 0) red[w] = local;
    __syncthreads();
    if (tid == 0) {
        float tsum = 0.0f;
        #pragma unroll
        for (int i = 0; i < 8; ++i) tsum += red[i];
        atomicAdd(loss_out, tsum);
    }
}

extern "C" void kernel_launch(void* const* d_in, const int* in_sizes, int n_in,
                              void* d_out, int out_size, void* d_ws, size_t ws_size,
                              hipStream_t stream) {
    const float* in1 = (const float*)d_in[0];
    const float* in2 = (const float*)d_in[1];
    float* out = (float*)d_out;
    int8_t* nrm = (int8_t*)d_ws;                   // 8192x1024 i8 = 8 MB

    norm_i8_kernel<<<(U_ROWS * 2) / 4, 256, 0, stream>>>(in1, in2, nrm, out);

    cosloss_gemm_i8<<<(U_ROWS / TM) * (U_ROWS / TN), 512, 0, stream>>>(
        nrm, nrm + (size_t)U_ROWS * P_DIM, out);
}

// Round 12
// 94.596 us; speedup vs baseline: 1.0477x; 1.0477x over previous
//
#include <hip/hip_runtime.h>
#include <hip/hip_bf16.h>
#include <stdint.h>

#define U_ROWS 4096
#define P_DIM  1024
#define TB     256     // block tile: 256x256
#define BK     64      // i8 k-bytes per window (2 k-steps of K=32)

typedef int i32x4  __attribute__((ext_vector_type(4)));
typedef int i32x16 __attribute__((ext_vector_type(16)));

// ===== SESSION-BEST CONFIGURATION (round 9, 95.1 us total) — reverted =====
// Probed alternatives all equal/worse: r8 3-blk/CU 16x16x64 (97.3),
// r10 16-wave BK=128 (97.7), r11 2-blk/CU 64x64-wave (99.1), r7 direct-L2
// (155), r4-6 MX-scaled (VGPR-bound, 119-304). GEMM sits at ~25 us = 31%
// of the 4404-TOPS i8 ubench ceiling, the m97-family source-level plateau
// (barrier vmcnt(0) drain; HIP-source pipelining attempts are
// compiler-defeated per m131-m141).

// Row L2-normalize (eps-clamped), quantize q = clamp(round(512*x/||x||)).
// Global layout: within each 64-byte k-window, granule g (16 B) stored at
// slot g ^ ((row>>1)&3) -> GEMM fragment ds_read_b128 covers all 32 LDS
// banks across 8 consecutive rows (conflict-free).
__global__ __launch_bounds__(256) void norm_i8_kernel(
    const float* __restrict__ in1, const float* __restrict__ in2,
    int8_t* __restrict__ out, float* __restrict__ loss_out) {
    const int w = threadIdx.x >> 6, lane = threadIdx.x & 63;
    const int row = blockIdx.x * 4 + w;
    const float* src = (row < U_ROWS) ? (in1 + (size_t)row * P_DIM)
                                      : (in2 + (size_t)(row - U_ROWS) * P_DIM);
    float4 v[4];
    float ss = 0.0f;
    #pragma unroll
    for (int j = 0; j < 4; ++j) {
        v[j] = ((const float4*)src)[lane * 4 + j];   // lane owns 16 elems
        ss += v[j].x * v[j].x + v[j].y * v[j].y + v[j].z * v[j].z + v[j].w * v[j].w;
    }
    #pragma unroll
    for (int off = 32; off > 0; off >>= 1) ss += __shfl_xor(ss, off, 64);
    const float inv = 512.0f / fmaxf(sqrtf(ss), 1e-8f);

    i32x4 d;
    #pragma unroll
    for (int j = 0; j < 4; ++j) {
        int q0 = max(-127, min(127, (int)rintf(v[j].x * inv)));
        int q1 = max(-127, min(127, (int)rintf(v[j].y * inv)));
        int q2 = max(-127, min(127, (int)rintf(v[j].z * inv)));
        int q3 = max(-127, min(127, (int)rintf(v[j].w * inv)));
        d[j] = (q0 & 255) | ((q1 & 255) << 8) | ((q2 & 255) << 16) | (q3 << 24);
    }
    const int w0   = lane >> 2;                  // 64-B k-window index 0..15
    const int g    = lane & 3;                   // granule within window
    const int slot = g ^ ((row >> 1) & 3);       // bank-spread swizzle
    *(i32x4*)(out + (size_t)row * P_DIM + w0 * 64 + slot * 16) = d;
    if (blockIdx.x == 0 && threadIdx.x == 0) *loss_out = 0.0f;
}

// C = N1*N2^T fused with sum((1-c)^2); int8 scaled by 512 -> acc = 2^18*cos
// (exact integer accumulation). Block 256x256, 512 thr / 8 waves, wave tile
// 128x64 via 4x2 v_mfma_i32_32x32x32_i8 per K=32 step (2 steps/window).
// Single-barrier double-buffered K-loop: barrier -> issue DMA(kt+1) into
// buf^1 -> compute on buf. LDS 64 KB, 1 block/CU, grid 256 (no tail).
// acc[4][2] i32x16 = 128 AGPRs (plain MFMA -> AGPR file, VGPR ~72).
__global__ __launch_bounds__(512) void cosloss_gemm_i8(
    const int8_t* __restrict__ n1, const int8_t* __restrict__ n2,
    float* __restrict__ loss_out) {
    __shared__ __align__(16) uint8_t As[2][TB * BK];   // 2 x 16 KB
    __shared__ __align__(16) uint8_t Bs[2][TB * BK];   // 2 x 16 KB  (=64 KB)

    const int tid  = threadIdx.x;
    const int w    = tid >> 6;        // 0..7
    const int lane = tid & 63;

    // XCD swizzle (perf-only): id%8 -> XCD; each XCD works 2 cb panels.
    const int id  = blockIdx.x;         // 0..255
    const int xcd = id & 7;
    const int t   = id >> 3;            // 0..31
    const int cb  = xcd * 2 + (t & 1);  // 0..15
    const int rb  = t >> 1;             // 0..15

    const uint8_t* gA = (const uint8_t*)n1 + (size_t)rb * TB * P_DIM;
    const uint8_t* gB = (const uint8_t*)n2 + (size_t)cb * TB * P_DIM;

    // Staging: chunk = 16 rows x 64 B (1 KB); 32 chunks (16 A + 16 B), 4/wave.
    // Lane reads LINEARLY (swizzle lives in the global layout).
    const int srow = lane >> 2;              // 0..15
    const int scol = (lane & 3) * 16;        // byte col within window
    const int c0   = w * 4;

    i32x16 acc[4][2];
    #pragma unroll
    for (int mi = 0; mi < 4; ++mi)
        #pragma unroll
        for (int ni = 0; ni < 2; ++ni)
            acc[mi][ni] = (i32x16){0,0,0,0,0,0,0,0,0,0,0,0,0,0,0,0};

    const int wr = (w & 1) * 128;     // wave row origin in 256
    const int wc = (w >> 1) * 64;     // wave col origin in 256
    const int lm = lane & 31;         // row within 32
    const int lh = lane >> 5;         // k-half selector

    // kt-invariant LDS fragment byte offsets (un-swizzle the granule):
    // frag (i, s): row m, wants granule g = 2s + lh, stored at g^((m>>1)&3).
    int aoff[4][2], boff[2][2];
    #pragma unroll
    for (int i = 0; i < 4; ++i) {
        const int m = wr + i * 32 + lm;
        #pragma unroll
        for (int s = 0; s < 2; ++s)
            aoff[i][s] = m * BK + (((2 * s + lh) ^ ((m >> 1) & 3)) * 16);
    }
    #pragma unroll
    for (int ni = 0; ni < 2; ++ni) {
        const int n = wc + ni * 32 + lm;
        #pragma unroll
        for (int s = 0; s < 2; ++s)
            boff[ni][s] = n * BK + (((2 * s + lh) ^ ((n >> 1) & 3)) * 16);
    }

    // Prologue: stage window 0 into buffer 0.
    #pragma unroll
    for (int cc = 0; cc < 4; ++cc) {
        const int c = c0 + cc;
        const uint8_t* gsrc = (c < 16)
            ? gA + (size_t)(c * 16 + srow) * P_DIM + scol
            : gB + (size_t)((c - 16) * 16 + srow) * P_DIM + scol;
        uint8_t* sdst = (c < 16) ? As[0] + c * 1024 : Bs[0] + (c - 16) * 1024;
        __builtin_amdgcn_global_load_lds(
            (const __attribute__((address_space(1))) void*)gsrc,
            (__attribute__((address_space(3))) void*)sdst, 16, 0, 0);
    }

    for (int kt = 0; kt < P_DIM / BK; ++kt) {
        const int cur = kt & 1;
        __syncthreads();   // DMA(kt) drained; buf[cur^1] reads all done

        if (kt + 1 < P_DIM / BK) {
            #pragma unroll
            for (int cc = 0; cc < 4; ++cc) {
                const int c = c0 + cc;
                const uint8_t* gsrc = (c < 16)
                    ? gA + (size_t)(c * 16 + srow) * P_DIM + (kt + 1) * BK + scol
                    : gB + (size_t)((c - 16) * 16 + srow) * P_DIM + (kt + 1) * BK + scol;
                uint8_t* sdst = (c < 16) ? As[cur ^ 1] + c * 1024
                                         : Bs[cur ^ 1] + (c - 16) * 1024;
                __builtin_amdgcn_global_load_lds(
                    (const __attribute__((address_space(1))) void*)gsrc,
                    (__attribute__((address_space(3))) void*)sdst, 16, 0, 0);
            }
        }

        #pragma unroll
        for (int s = 0; s < 2; ++s) {
            i32x4 af[4], bf[2];
            #pragma unroll
            for (int i = 0; i < 4; ++i)
                af[i] = *(const i32x4*)(As[cur] + aoff[i][s]);
            #pragma unroll
            for (int ni = 0; ni < 2; ++ni)
                bf[ni] = *(const i32x4*)(Bs[cur] + boff[ni][s]);
            #pragma unroll
            for (int mi = 0; mi < 4; ++mi)
                #pragma unroll
                for (int ni = 0; ni < 2; ++ni)
                    acc[mi][ni] = __builtin_amdgcn_mfma_i32_32x32x32_i8(
                        af[mi], bf[ni], acc[mi][ni], 0, 0, 0);
        }
    }

    // Epilogue: acc = 2^18 * cos -> sum (1 - acc*2^-18)^2. Layout-agnostic
    // (full-tile sum; every C element appears exactly once).
    float local = 0.0f;
    #pragma unroll
    for (int mi = 0; mi < 4; ++mi)
        #pragma unroll
        for (int ni = 0; ni < 2; ++ni)
            #pragma unroll
            for (int r = 0; r < 16; ++r) {
                const float dd = 1.0f - (float)acc[mi][ni][r] * (1.0f / 262144.0f);
                local += dd * dd;
            }
    #pragma unroll
    for (int off = 32; off > 0; off >>= 1) local += __shfl_down(local, off, 64);

    __syncthreads();                       // done with LDS tiles
    float* redf = (float*)As;              // reuse LDS for reduction
    if (lane == 0) redf[w] = local;
    __syncthreads();
    if (tid == 0) {
        float tsum = 0.0f;
        #pragma unroll
        for (int i = 0; i < 8; ++i) tsum += redf[i];
        atomicAdd(loss_out, tsum);
    }
}

extern "C" void kernel_launch(void* const* d_in, const int* in_sizes, int n_in,
                              void* d_out, int out_size, void* d_ws, size_t ws_size,
                              hipStream_t stream) {
    const float* in1 = (const float*)d_in[0];
    const float* in2 = (const float*)d_in[1];
    float* out = (float*)d_out;
    int8_t* nrm = (int8_t*)d_ws;                   // 8192x1024 i8 = 8 MB

    norm_i8_kernel<<<(U_ROWS * 2) / 4, 256, 0, stream>>>(in1, in2, nrm, out);

    cosloss_gemm_i8<<<(U_ROWS / TB) * (U_ROWS / TB), 512, 0, stream>>>(
        nrm, nrm + (size_t)U_ROWS * P_DIM, out);
}